// Round 1
// baseline (325.378 us; speedup 1.0000x reference)
//
#include <hip/hip_runtime.h>

// out[b, p, k, :, :] = x[b, p, PERM[k], :, :]
// x: (16, 3*64, 128, 128) fp32.  Each channel slice = 128*128 = 16384 floats
// = 4096 float4 (contiguous).  PERM = inverse zigzag (JPEG scan order) for 8x8.
__constant__ int d_perm[64] = {
     0,  1,  8, 16,  9,  2,  3, 10,
    17, 24, 32, 25, 18, 11,  4,  5,
    12, 19, 26, 33, 40, 48, 41, 34,
    27, 20, 13,  6,  7, 14, 21, 28,
    35, 42, 49, 56, 57, 50, 43, 36,
    29, 22, 15, 23, 30, 37, 44, 51,
    58, 59, 52, 45, 38, 31, 39, 46,
    53, 60, 61, 54, 47, 55, 62, 63
};

__global__ __launch_bounds__(256) void zigzag_perm_kernel(
    const float4* __restrict__ in, float4* __restrict__ out, int total4)
{
    int idx    = blockIdx.x * blockDim.x + threadIdx.x;
    int stride = gridDim.x * blockDim.x;
    for (int f = idx; f < total4; f += stride) {
        int slice  = f >> 12;      // / 4096 float4 per channel slice
        int within = f & 4095;
        int k      = slice & 63;   // channel index within the 64-group
        int src    = ((slice - k + d_perm[k]) << 12) + within;
        out[f] = in[src];
    }
}

extern "C" void kernel_launch(void* const* d_in, const int* in_sizes, int n_in,
                              void* d_out, int out_size, void* d_ws, size_t ws_size,
                              hipStream_t stream) {
    const float4* in  = (const float4*)d_in[0];
    float4*       out = (float4*)d_out;
    int total4 = out_size / 4;           // 50,331,648 / 4 = 12,582,912
    int block  = 256;
    int grid   = 2048;                   // grid-stride, ~24 iters/thread
    zigzag_perm_kernel<<<grid, block, 0, stream>>>(in, out, total4);
}